// Round 5
// baseline (467.417 us; speedup 1.0000x reference)
//
#include <hip/hip_runtime.h>
#include <hip/hip_bf16.h>
#include <math.h>

#define NSAMP 8
#define BATCH 1024
#define PH 12
#define XS 256
#define ZS 32
#define RNN 512
#define LSZ 8
#define INP 290          // LPS + ZS + XS
#define NTOT 8192        // NSAMP * BATCH
#define DT 0.4f

// output layout (flat f32, concatenated in return order)
#define LOGPI_OFF 0
#define MUS_OFF   (NTOT*PH)               // 98304
#define LSIG_OFF  (MUS_OFF + NTOT*PH*2)   // 294912
#define CORR_OFF  (LSIG_OFF + NTOT*PH*2)  // 491520
#define PRED_OFF  (CORR_OFF + NTOT*PH)    // 589824

typedef float f32x4 __attribute__((ext_vector_type(4)));
typedef __bf16 bf16x8 __attribute__((ext_vector_type(8)));

__device__ __forceinline__ float sigmoid_(float x) {
    return 1.0f / (1.0f + __expf(-x));
}
__device__ __forceinline__ float tanh_(float x) {
    return 1.0f - 2.0f / (__expf(2.0f * x) + 1.0f);
}

__device__ __forceinline__ void async16(const void* g, void* l) {
    __builtin_amdgcn_global_load_lds((const __attribute__((address_space(1))) void*)g,
                                     (__attribute__((address_space(3))) void*)l, 16, 0, 0);
}

// ---------------- small prep kernels ----------------

__global__ void k_init_a(const float* __restrict__ x_r_t0,
                         const float* __restrict__ W_sa,
                         const float* __restrict__ b_sa,
                         float* __restrict__ a) {
    int n = blockIdx.x * blockDim.x + threadIdx.x;
    if (n >= NTOT) return;
    int b = n & (BATCH - 1);
    float a0 = b_sa[0], a1 = b_sa[1];
#pragma unroll
    for (int k = 0; k < LSZ; ++k) {
        float xv = x_r_t0[b * LSZ + k];
        a0 = fmaf(xv, W_sa[0 * LSZ + k], a0);
        a1 = fmaf(xv, W_sa[1 * LSZ + k], a1);
    }
    a[n * 2 + 0] = a0;
    a[n * 2 + 1] = a1;
}

// zx_bf16[n][288] = [z[n,0:32], x[n%B,0:256]]
__global__ void k_cast_zx(const float* __restrict__ z, const float* __restrict__ x,
                          __hip_bfloat16* __restrict__ zx) {
    int n = blockIdx.x, k = threadIdx.x;
    if (k >= 288) return;
    float v = (k < 32) ? z[n * ZS + k] : x[(n & (BATCH - 1)) * XS + (k - 32)];
    zx[(size_t)n * 288 + k] = __float2bfloat16(v);
}

// Wcat[2048][288]: rows<512 = W_h0, rows>=512 = W_ih[:, :288] (stride 290)
__global__ void k_cast_w(const float* __restrict__ W_h0, const float* __restrict__ W_ih,
                         __hip_bfloat16* __restrict__ Wcat) {
    int r = blockIdx.x, k = threadIdx.x;
    if (k >= 288) return;
    float v = (r < RNN) ? W_h0[r * 288 + k] : W_ih[(size_t)(r - RNN) * INP + k];
    Wcat[(size_t)r * 288 + k] = __float2bfloat16(v);
}

__global__ void k_cast_whh(const float* __restrict__ W, __hip_bfloat16* __restrict__ Wb) {
    int i = blockIdx.x * 256 + threadIdx.x;   // grid covers 1536*512
    Wb[i] = __float2bfloat16(W[i]);
}

// ---------------- GEMM0: [h0 | gi_zx] = zx @ Wcat^T + bias ----------------
__global__ __launch_bounds__(256, 2) void k_gemm0_mfma(
    const __hip_bfloat16* __restrict__ zx, const __hip_bfloat16* __restrict__ Wcat,
    const float* __restrict__ b_h0, const float* __restrict__ b_ih,
    __hip_bfloat16* __restrict__ h0, __hip_bfloat16* __restrict__ gi)
{
    __shared__ __align__(16) char sA[8192];   // [128][32] bf16, slot-swizzled
    __shared__ __align__(16) char sB[8192];
    const int tid = threadIdx.x;
    const int wv = tid >> 6, lane = tid & 63;
    const int fq = lane >> 4, fr = lane & 15;
    const int wr = wv >> 1, wc = wv & 1;
    const int tile_r = blockIdx.x * 128, tile_c = blockIdx.y * 128;

    f32x4 acc[4][4];
#pragma unroll
    for (int i = 0; i < 4; ++i)
#pragma unroll
        for (int j = 0; j < 4; ++j) acc[i][j] = (f32x4){0.f, 0.f, 0.f, 0.f};

    for (int k0 = 0; k0 < 288; k0 += 32) {
#pragma unroll
        for (int j = 0; j < 2; ++j) {
            int ck = wv * 2 + j;
            int row = ck * 16 + (lane >> 2);
            int slot = lane & 3;
            async16(zx + (size_t)(tile_r + row) * 288 + k0 + ((slot ^ (row & 3)) << 3),
                    sA + ck * 1024 + lane * 16);
        }
#pragma unroll
        for (int j = 0; j < 2; ++j) {
            int ck = wv * 2 + j;
            int row = ck * 16 + (lane >> 2);
            int slot = lane & 3;
            async16(Wcat + (size_t)(tile_c + row) * 288 + k0 + ((slot ^ (row & 3)) << 3),
                    sB + ck * 1024 + lane * 16);
        }
        __syncthreads();
        bf16x8 af[4], bv[4];
#pragma unroll
        for (int i = 0; i < 4; ++i) {
            int r = wr * 64 + i * 16 + fr;
            af[i] = *(const bf16x8*)(sA + r * 64 + ((fq ^ (r & 3)) << 4));
        }
#pragma unroll
        for (int j = 0; j < 4; ++j) {
            int r = wc * 64 + j * 16 + fr;
            bv[j] = *(const bf16x8*)(sB + r * 64 + ((fq ^ (r & 3)) << 4));
        }
#pragma unroll
        for (int i = 0; i < 4; ++i)
#pragma unroll
            for (int j = 0; j < 4; ++j)
                acc[i][j] = __builtin_amdgcn_mfma_f32_16x16x32_bf16(af[i], bv[j], acc[i][j], 0, 0, 0);
        __syncthreads();
    }

#pragma unroll
    for (int jn = 0; jn < 4; ++jn) {
        int cg = tile_c + wc * 64 + jn * 16 + fr;
        float bias = (cg < RNN) ? b_h0[cg] : b_ih[cg - RNN];
#pragma unroll
        for (int i = 0; i < 4; ++i)
#pragma unroll
            for (int q = 0; q < 4; ++q) {
                int rg = tile_r + wr * 64 + i * 16 + fq * 4 + q;
                float v = acc[i][jn][q] + bias;
                if (cg < RNN) h0[(size_t)rg * RNN + cg] = __float2bfloat16(v);
                else          gi[(size_t)rg * 1536 + (cg - RNN)] = __float2bfloat16(v);
            }
    }
}

// ---------------- fused GRU step (MFMA, 2-phase) + heads partials ----------------
// Block: 256 rows x 64 h-cols x 3 gates. 8 waves (4x2) -> wave = 64 rows x (32 cols x 3 gates).
// Epilogue also accumulates the 5 head GEMV partials over this block's 64-col slice
// and writes them to partial[row][blockIdx.y*2 + wc][5]  (16 slices per row, f32).
#define GRU_LDS_A 32768
#define GRU_LDS_BUF 57344
__global__ __launch_bounds__(512, 1) void k_gru_step_mfma(
    const __hip_bfloat16* __restrict__ h, const float* __restrict__ a,
    const __hip_bfloat16* __restrict__ gi,
    const __hip_bfloat16* __restrict__ Whh, const float* __restrict__ b_hh,
    const float* __restrict__ W_ih,
    const float* __restrict__ W_mu, const float* __restrict__ W_ls,
    const float* __restrict__ W_corr,
    __hip_bfloat16* __restrict__ h_new, float* __restrict__ partial)
{
    __shared__ __align__(16) char lds[2][GRU_LDS_BUF];
    const int tid = threadIdx.x;
    const int wv = tid >> 6, lane = tid & 63;
    const int fq = lane >> 4, fr = lane & 15;
    const int wr = wv >> 1, wc = wv & 1;
    const int tile_r = blockIdx.x * 256;
    const int tile_c = blockIdx.y * 64;

    f32x4 acc[3][4][2];
#pragma unroll
    for (int g = 0; g < 3; ++g)
#pragma unroll
        for (int i = 0; i < 4; ++i)
#pragma unroll
            for (int j = 0; j < 2; ++j) acc[g][i][j] = (f32x4){0.f, 0.f, 0.f, 0.f};

    const int lrow = lane >> 2;
    const int slot = (lane & 3) ^ (lrow & 3);     // XOR slot swizzle (both sides)

    auto stage = [&](int b, int k0) {
#pragma unroll
        for (int j = 0; j < 7; ++j) {
            int c = wv * 7 + j;
            if (c < 32) {
                int rowgrp = c >> 1, kh = c & 1;
                int row = tile_r + rowgrp * 16 + lrow;
                async16(h + (size_t)row * RNN + k0 + kh * 32 + slot * 8,
                        lds[b] + c * 1024 + lane * 16);
            } else {
                int cp = c - 32;
                int grp = cp >> 1, kh = cp & 1;
                int rB = grp * 16 + lrow;
                int gate = rB >> 6, col = rB & 63;
                async16(Whh + (size_t)(gate * RNN + tile_c + col) * RNN + k0 + kh * 32 + slot * 8,
                        lds[b] + GRU_LDS_A + cp * 1024 + lane * 16);
            }
        }
    };

    auto compute = [&](int b) {
        const char* bufA = lds[b];
        const char* bufB = lds[b] + GRU_LDS_A;
        const int rsw = (fq ^ (fr & 3)) << 4;
#pragma unroll
        for (int ks = 0; ks < 2; ++ks) {
            bf16x8 af[4];
#pragma unroll
            for (int i = 0; i < 4; ++i) {
                int chunk = (wr * 4 + i) * 2 + ks;
                af[i] = *(const bf16x8*)(bufA + chunk * 1024 + fr * 64 + rsw);
            }
            bf16x8 bv[3][2];
#pragma unroll
            for (int g = 0; g < 3; ++g)
#pragma unroll
                for (int j = 0; j < 2; ++j) {
                    int grp = g * 4 + wc * 2 + j;
                    int chunk = grp * 2 + ks;
                    bv[g][j] = *(const bf16x8*)(bufB + chunk * 1024 + fr * 64 + rsw);
                }
#pragma unroll
            for (int g = 0; g < 3; ++g)
#pragma unroll
                for (int i = 0; i < 4; ++i)
#pragma unroll
                    for (int j = 0; j < 2; ++j)
                        acc[g][i][j] = __builtin_amdgcn_mfma_f32_16x16x32_bf16(
                            af[i], bv[g][j], acc[g][i][j], 0, 0, 0);
        }
    };

    stage(0, 0);
    __syncthreads();
    int buf = 0;
#pragma unroll 1
    for (int t = 0; t < 7; ++t) {
        stage(buf ^ 1, (t + 1) * 64);   // issue next-tile loads BEFORE compute
        compute(buf);
        __syncthreads();
        buf ^= 1;
    }
    compute(buf);

    // ---- fused GRU epilogue + head partials ----
    int cg[2];
    float bhr[2], bhz[2], bhn[2];
    float wr0[2], wr1[2], wz0[2], wz1[2], wn0[2], wn1[2];
    float wmu0[2], wmu1[2], wls0[2], wls1[2], wcor[2];
#pragma unroll
    for (int j = 0; j < 2; ++j) {
        const int c = tile_c + wc * 32 + j * 16 + fr;
        cg[j] = c;
        bhr[j] = b_hh[c]; bhz[j] = b_hh[RNN + c]; bhn[j] = b_hh[2 * RNN + c];
        wr0[j] = W_ih[(size_t)c * INP + 288];             wr1[j] = W_ih[(size_t)c * INP + 289];
        wz0[j] = W_ih[(size_t)(RNN + c) * INP + 288];     wz1[j] = W_ih[(size_t)(RNN + c) * INP + 289];
        wn0[j] = W_ih[(size_t)(2 * RNN + c) * INP + 288]; wn1[j] = W_ih[(size_t)(2 * RNN + c) * INP + 289];
        wmu0[j] = W_mu[c]; wmu1[j] = W_mu[RNN + c];
        wls0[j] = W_ls[c]; wls1[j] = W_ls[RNN + c];
        wcor[j] = W_corr[c];
    }
    const int slice = (blockIdx.y << 1) + wc;      // 0..15

#pragma unroll
    for (int i = 0; i < 4; ++i)
#pragma unroll
        for (int q = 0; q < 4; ++q) {
            const int rg = tile_r + wr * 64 + i * 16 + fq * 4 + q;
            const float2 av = *(const float2*)&a[rg * 2];
            float p0 = 0.f, p1 = 0.f, p2 = 0.f, p3 = 0.f, p4 = 0.f;
#pragma unroll
            for (int j = 0; j < 2; ++j) {
                const float gr = __bfloat162float(gi[(size_t)rg * 1536 + cg[j]])
                                 + av.x * wr0[j] + av.y * wr1[j] + acc[0][i][j][q] + bhr[j];
                const float gz = __bfloat162float(gi[(size_t)rg * 1536 + RNN + cg[j]])
                                 + av.x * wz0[j] + av.y * wz1[j] + acc[1][i][j][q] + bhz[j];
                const float gn = __bfloat162float(gi[(size_t)rg * 1536 + 2 * RNN + cg[j]])
                                 + av.x * wn0[j] + av.y * wn1[j];
                const float r_ = sigmoid_(gr);
                const float u_ = sigmoid_(gz);
                const float n_ = tanh_(gn + r_ * (acc[2][i][j][q] + bhn[j]));
                const float hv = __bfloat162float(h[(size_t)rg * RNN + cg[j]]);
                const float hnew = (1.0f - u_) * n_ + u_ * hv;
                h_new[(size_t)rg * RNN + cg[j]] = __float2bfloat16(hnew);
                p0 = fmaf(hnew, wmu0[j], p0);
                p1 = fmaf(hnew, wmu1[j], p1);
                p2 = fmaf(hnew, wls0[j], p2);
                p3 = fmaf(hnew, wls1[j], p3);
                p4 = fmaf(hnew, wcor[j], p4);
            }
#pragma unroll
            for (int m = 1; m <= 8; m <<= 1) {
                p0 += __shfl_xor(p0, m, 64);
                p1 += __shfl_xor(p1, m, 64);
                p2 += __shfl_xor(p2, m, 64);
                p3 += __shfl_xor(p3, m, 64);
                p4 += __shfl_xor(p4, m, 64);
            }
            if (fr == 0) {
                float* pr = partial + ((size_t)rg * 16 + slice) * 5;
                pr[0] = p0; pr[1] = p1; pr[2] = p2; pr[3] = p3; pr[4] = p4;
            }
        }
}

// ---------------- heads finalize: sum 16 slices, outputs + sample a ----------------
__global__ __launch_bounds__(256) void k_heads_fin(
    const float* __restrict__ partial,
    const float* __restrict__ b_mu, const float* __restrict__ b_ls,
    const float* __restrict__ b_corr,
    const float* __restrict__ eps_step_t,
    float* __restrict__ out, float* __restrict__ a, int t)
{
    const int n = blockIdx.x * blockDim.x + threadIdx.x;
    if (n >= NTOT) return;
    const float* pr = partial + (size_t)n * 80;
    float s0 = 0.f, s1 = 0.f, s2 = 0.f, s3 = 0.f, s4 = 0.f;
#pragma unroll
    for (int sl = 0; sl < 16; ++sl) {
        const float4 v0 = *reinterpret_cast<const float4*>(pr + sl * 5);
        s0 += v0.x; s1 += v0.y; s2 += v0.z; s3 += v0.w;
        s4 += pr[sl * 5 + 4];
    }
    const float mu0 = s0 + b_mu[0], mu1 = s1 + b_mu[1];
    const float ls0 = s2 + b_ls[0], ls1 = s3 + b_ls[1];
    const float rho = tanh_(s4 + b_corr[0]);
    out[MUS_OFF + (n * PH + t) * 2 + 0] = mu0;
    out[MUS_OFF + (n * PH + t) * 2 + 1] = mu1;
    out[LSIG_OFF + (n * PH + t) * 2 + 0] = ls0;
    out[LSIG_OFF + (n * PH + t) * 2 + 1] = ls1;
    out[CORR_OFF + n * PH + t] = rho;
    const float e0 = eps_step_t[n * 2 + 0], e1 = eps_step_t[n * 2 + 1];
    const float sg0 = __expf(ls0), sg1 = __expf(ls1);
    a[n * 2 + 0] = mu0 + sg0 * e0;
    a[n * 2 + 1] = mu1 + sg1 * (rho * e0 + sqrtf(fmaxf(1e-5f, 1.0f - rho * rho)) * e1);
}

// ---------------- final: sample + cumsum + log_pis ----------------
__global__ void k_final(const float* __restrict__ p0,
                        const float* __restrict__ eps_final,
                        float* __restrict__ out)
{
    int n = blockIdx.x * blockDim.x + threadIdx.x;
    if (n >= NTOT) return;
    const int b = n & (BATCH - 1);
    const float px = p0[b * 2 + 0], py = p0[b * 2 + 1];
    float cx = 0.f, cy = 0.f;
#pragma unroll
    for (int t = 0; t < PH; ++t) {
        const float mu0 = out[MUS_OFF + (n * PH + t) * 2 + 0];
        const float mu1 = out[MUS_OFF + (n * PH + t) * 2 + 1];
        const float ls0 = out[LSIG_OFF + (n * PH + t) * 2 + 0];
        const float ls1 = out[LSIG_OFF + (n * PH + t) * 2 + 1];
        const float rho = out[CORR_OFF + n * PH + t];
        const float e0 = eps_final[(n * PH + t) * 2 + 0];
        const float e1 = eps_final[(n * PH + t) * 2 + 1];
        const float sg0 = __expf(ls0), sg1 = __expf(ls1);
        cx += mu0 + sg0 * e0;
        cy += mu1 + sg1 * (rho * e0 + sqrtf(fmaxf(1e-5f, 1.0f - rho * rho)) * e1);
        out[PRED_OFF + (n * PH + t) * 2 + 0] = cx * DT + px;
        out[PRED_OFF + (n * PH + t) * 2 + 1] = cy * DT + py;
        out[LOGPI_OFF + n * PH + t] = 1.0f;
    }
}

extern "C" void kernel_launch(void* const* d_in, const int* in_sizes, int n_in,
                              void* d_out, int out_size, void* d_ws, size_t ws_size,
                              hipStream_t stream) {
    const float* x        = (const float*)d_in[0];
    const float* x_r_t0   = (const float*)d_in[1];
    const float* z        = (const float*)d_in[2];
    const float* p0       = (const float*)d_in[3];
    const float* eps_step = (const float*)d_in[4];
    const float* eps_fin  = (const float*)d_in[5];
    const float* W_sa     = (const float*)d_in[6];
    const float* b_sa     = (const float*)d_in[7];
    const float* W_ih     = (const float*)d_in[8];
    const float* b_ih     = (const float*)d_in[9];
    const float* W_hh     = (const float*)d_in[10];
    const float* b_hh     = (const float*)d_in[11];
    const float* W_h0     = (const float*)d_in[12];
    const float* b_h0     = (const float*)d_in[13];
    const float* W_mu     = (const float*)d_in[14];
    const float* b_mu     = (const float*)d_in[15];
    const float* W_ls     = (const float*)d_in[16];
    const float* b_ls     = (const float*)d_in[17];
    const float* W_corr   = (const float*)d_in[18];
    const float* b_corr   = (const float*)d_in[19];

    char* wp = (char*)d_ws;
    float* a            = (float*)wp;          wp += (size_t)NTOT * 2 * 4;
    float* partial      = (float*)wp;          wp += (size_t)NTOT * 16 * 5 * 4;
    __hip_bfloat16* zxb = (__hip_bfloat16*)wp; wp += (size_t)NTOT * 288 * 2;
    __hip_bfloat16* Wcat= (__hip_bfloat16*)wp; wp += (size_t)2048 * 288 * 2;
    __hip_bfloat16* Whhb= (__hip_bfloat16*)wp; wp += (size_t)1536 * RNN * 2;
    __hip_bfloat16* h0  = (__hip_bfloat16*)wp; wp += (size_t)NTOT * RNN * 2;
    __hip_bfloat16* h1  = (__hip_bfloat16*)wp; wp += (size_t)NTOT * RNN * 2;
    __hip_bfloat16* gi  = (__hip_bfloat16*)wp; wp += (size_t)NTOT * 1536 * 2;
    float* out = (float*)d_out;

    k_init_a<<<dim3(NTOT / 256), dim3(256), 0, stream>>>(x_r_t0, W_sa, b_sa, a);
    k_cast_zx<<<dim3(NTOT), dim3(320), 0, stream>>>(z, x, zxb);
    k_cast_w<<<dim3(2048), dim3(320), 0, stream>>>(W_h0, W_ih, Wcat);
    k_cast_whh<<<dim3(1536 * RNN / 256), dim3(256), 0, stream>>>(W_hh, Whhb);
    k_gemm0_mfma<<<dim3(64, 16), dim3(256), 0, stream>>>(zxb, Wcat, b_h0, b_ih, h0, gi);

    __hip_bfloat16* hc = h0;
    __hip_bfloat16* hn = h1;
    for (int t = 0; t < PH; ++t) {
        k_gru_step_mfma<<<dim3(NTOT / 256, RNN / 64), dim3(512), 0, stream>>>(
            hc, a, gi, Whhb, b_hh, W_ih, W_mu, W_ls, W_corr, hn, partial);
        k_heads_fin<<<dim3(NTOT / 256), dim3(256), 0, stream>>>(
            partial, b_mu, b_ls, b_corr,
            eps_step + (size_t)t * NTOT * 2, out, a, t);
        __hip_bfloat16* tmp = hc; hc = hn; hn = tmp;
    }
    k_final<<<dim3(NTOT / 256), dim3(256), 0, stream>>>(p0, eps_fin, out);
}